// Round 9
// baseline (61.983 us; speedup 1.0000x reference)
//
#include <hip/hip_runtime.h>
#include <hip/hip_bf16.h>
#include <math.h>

using bf16x8 = __attribute__((ext_vector_type(8))) __bf16;
using bf16x4 = __attribute__((ext_vector_type(4))) __bf16;
using f32x4  = __attribute__((ext_vector_type(4))) float;
using f32x16 = __attribute__((ext_vector_type(16))) float;

static constexpr int SEQ = 4096;
static constexpr int DIM = 64;
static constexpr int NB  = 4;
// 0.125 (1/sqrt(64)) * log2(e): scores in log2 domain -> exp2 everywhere
static constexpr float QSCALE = 0.18033688011112042f;

__device__ __forceinline__ void gload16(const void* g, void* l) {
    __builtin_amdgcn_global_load_lds(
        (const __attribute__((address_space(1))) unsigned int*)g,
        (__attribute__((address_space(3))) unsigned int*)l,
        16, 0, 0);
}

__device__ __forceinline__ float fast_exp2(float x) {
#if __has_builtin(__builtin_amdgcn_exp2f)
    return __builtin_amdgcn_exp2f(x);
#else
    return exp2f(x);
#endif
}

// ---------------------------------------------------------------------------
// Kernel 0a: cast+transpose W -> WT[slot][out][d] bf16.
// ---------------------------------------------------------------------------
__global__ __launch_bounds__(256)
void wprep_kernel(const float* __restrict__ w, __bf16* __restrict__ WT)
{
    const int idx = (int)blockIdx.x * 256 + (int)threadIdx.x;  // < 3*64*64
    const int s = idx >> 12;
    const int o = (idx >> 6) & 63;
    const int d = idx & 63;
    WT[idx] = (__bf16)w[(s * DIM + d) * DIM + o];
}

// ---------------------------------------------------------------------------
// Kernel 0b: pos-embed table peb[spos][c] = sin(spos * invf(c)), f32 [4096][64].
// Same __sinf / same args as the previous in-prep computation -> identical values.
// ---------------------------------------------------------------------------
__global__ __launch_bounds__(256)
void pe_prep_kernel(float* __restrict__ peb)
{
    const int idx = (int)blockIdx.x * 256 + (int)threadIdx.x;  // < SEQ*DIM
    const int spos = idx >> 6;
    const int c    = idx & 63;
    const float invf = exp2f(-13.287712379549449f * ((float)c * 0.03125f));
    peb[idx] = __sinf((float)spos * invf);
}

// ---------------------------------------------------------------------------
// Kernel 1: fused pos-embed + QKV projection. Block 256 thr (4 waves), wave
// owns 16 rows. Q pre-scaled by QSCALE (log2 domain), row-major. K row-major.
// V written FRAGMENT-MAJOR for the attention PV B-operand:
//   frag (kc, ks, n0) lane l elem e = V[kc*32 + ks*16 + (e&3)+8*(e>>2)+4*(l>>5)]
//                                      [n0*32 + (l&31)]
// From prep's C-layout acc[nt][r] (lane g,cl; row = rowbase+4g+r, col = nt*16+cl):
//   dest lane l = 32*(g&1) + 16*(nt&1) + cl, elem e = 4*(g>>1) + r  (verified).
// ---------------------------------------------------------------------------
__global__ __launch_bounds__(256)
void qkv_prep_kernel(const float* __restrict__ x, const __bf16* __restrict__ WT,
                     const float* __restrict__ peb,
                     __bf16* __restrict__ Qb, __bf16* __restrict__ Kb,
                     __bf16* __restrict__ Vf)
{
    const int tid  = (int)threadIdx.x;
    const int lane = tid & 63;
    const int g  = lane >> 4;
    const int cl = lane & 15;
    const int rowbase = (int)blockIdx.x * 64 + (tid >> 6) * 16;  // in [0, B*S)

    const int row  = rowbase + cl;
    const int spos = row & (SEQ - 1);
    bf16x8 xa[2];
#pragma unroll
    for (int h = 0; h < 2; ++h) {
        const float* xp = x + (long)row * DIM + 32*h + 8*g;
        const float* pp = peb + (long)spos * DIM + 32*h + 8*g;
        f32x4 x0 = *reinterpret_cast<const f32x4*>(xp);
        f32x4 x1 = *reinterpret_cast<const f32x4*>(xp + 4);
        f32x4 p0 = *reinterpret_cast<const f32x4*>(pp);
        f32x4 p1 = *reinterpret_cast<const f32x4*>(pp + 4);
        bf16x8 v;
#pragma unroll
        for (int e = 0; e < 8; ++e) {
            const float xv = (e < 4) ? x0[e] : x1[e - 4];
            const float pe = (e < 4) ? p0[e] : p1[e - 4];
            v[e] = (__bf16)(xv + pe);
        }
        xa[h] = v;
    }

#pragma unroll
    for (int slot = 0; slot < 3; ++slot) {
        const __bf16* wt = WT + slot * DIM * DIM;
        f32x4 acc[4];
#pragma unroll
        for (int nt = 0; nt < 4; ++nt) acc[nt] = (f32x4){0.f, 0.f, 0.f, 0.f};
#pragma unroll
        for (int nt = 0; nt < 4; ++nt) {
            bf16x8 w0 = *reinterpret_cast<const bf16x8*>(wt + (nt*16 + cl) * DIM + 8*g);
            bf16x8 w1 = *reinterpret_cast<const bf16x8*>(wt + (nt*16 + cl) * DIM + 32 + 8*g);
            acc[nt] = __builtin_amdgcn_mfma_f32_16x16x32_bf16(xa[0], w0, acc[nt], 0, 0, 0);
            acc[nt] = __builtin_amdgcn_mfma_f32_16x16x32_bf16(xa[1], w1, acc[nt], 0, 0, 0);
        }

        // C/D layout (HW-verified): lane l, reg r -> row (l>>4)*4+r, col l&15.
        if (slot < 2) {
            __bf16* dst = (slot == 0) ? Qb : Kb;
            const float scale = (slot == 0) ? QSCALE : 1.0f;
#pragma unroll
            for (int nt = 0; nt < 4; ++nt)
#pragma unroll
                for (int r = 0; r < 4; ++r) {
                    const int ro = rowbase + 4*g + r;
                    dst[(long)ro * DIM + nt*16 + cl] = (__bf16)(acc[nt][r] * scale);
                }
        } else {
            const int bi = rowbase >> 12;
            const int sp = rowbase & (SEQ - 1);
            const int kc = sp >> 5;
            const int ks = (sp >> 4) & 1;
            // elem offset within (kc,ks) pair region; +512 per n0, +128 for nt&1
            const int lde = (32*(g&1) + cl)*8 + (g>>1)*4;
            __bf16* vb = Vf + (((long)bi*128 + kc)*4 + ks*2)*512;
#pragma unroll
            for (int nt = 0; nt < 4; ++nt) {
                bf16x4 pk;
#pragma unroll
                for (int r = 0; r < 4; ++r) pk[r] = (__bf16)acc[nt][r];
                *reinterpret_cast<bf16x4*>(vb + (nt>>1)*512 + (nt&1)*128 + lde) = pk;
            }
        }
    }
}

// ---------------------------------------------------------------------------
// Kernel 2: flash attention, BARRIER-FREE main loop, 32x32x16 MFMA.
// Block = 4 independent waves (256 thr), all on the SAME 32 q-rows; wave w
// owns k-quarter [w*1024, +1024), 32 iters of 32 k. Per iter (per wave):
//   issue 4 gload_lds (K chunk n+1 -> wave-PRIVATE LDS buf, linear dest,
//   inverse-XOR-swizzled global source) + 4 coalesced 1KB V-frag reg loads
//   (n+1, frag-major Vf) -> s_waitcnt vmcnt(8) (counted: waits only for the
//   PREVIOUS iter's 8) -> 4 ds_read K-frags -> 4 QK MFMA -> in-lane softmax
//   (1 shfl_xor) -> in-lane P pack (k-pattern == C-layout, NO shuffles) ->
//   4 PV MFMA. No __syncthreads in the loop: waves drift freely, phases
//   interleave across the CU.
// Swapped QK (mfma(K,Q)): lane holds 16 scores of q=lane&31 at
// k = (r&3)+8*(r>>2)+4*(lane>>5). End: 4-way merge via LDS (2 barriers).
// grid = 512 (2 blocks/CU), XCD-batch swizzle b = f(bid&7).
// ---------------------------------------------------------------------------
__global__ __launch_bounds__(256)
void attn_kernel(const __bf16* __restrict__ Qb, const __bf16* __restrict__ Kb,
                 const __bf16* __restrict__ Vf, float* __restrict__ out)
{
    __shared__ char smem[32768];   // 4 waves x 2 bufs x 4KB K

    const int tid  = (int)threadIdx.x;
    const int w    = tid >> 6;
    const int lane = tid & 63;
    const int hi   = lane >> 5;
    const int l31  = lane & 31;

    const int bid = (int)blockIdx.x;
    const int x8  = bid & 7;
    const int b   = x8 & 3;
    const int qt  = ((x8 >> 2) << 6) | (bid >> 3);   // [0,128), bijective
    const int qbase = qt * 32;

    const __bf16* Qp  = Qb + ((long)b * SEQ + qbase) * DIM;
    const __bf16* Kp  = Kb + ((long)b * SEQ + w * 1024) * DIM;
    const __bf16* Vfp = Vf + (((long)b * 128 + w * 32) * 4) * 512;

    // Q fragments (once): lane l31 row, d = d4*16 + 8*hi + e
    bf16x8 qf[4];
#pragma unroll
    for (int d4 = 0; d4 < 4; ++d4)
        qf[d4] = *reinterpret_cast<const bf16x8*>(Qp + l31*DIM + d4*16 + 8*hi);

    // K staging geometry (wave-private): inst j writes LDS rows j*8..j*8+7
    // linearly; global source chunk is XOR-preswizzled.
    char* kbase = smem + w * 8192;
    const int srow = lane >> 3;              // 0..7
    const int ssw  = ((lane & 7) ^ srow) * 8;  // source chunk elems
    // ds_read byte offsets per frag d4 (swizzled read address)
    int rdo[4];
#pragma unroll
    for (int d4 = 0; d4 < 4; ++d4)
        rdo[d4] = l31*128 + (((2*d4 + hi) ^ (l31 & 7)) * 16);

    f32x16 acc[2];
#pragma unroll
    for (int n0 = 0; n0 < 2; ++n0)
#pragma unroll
        for (int r = 0; r < 16; ++r) acc[n0][r] = 0.f;
    float mrun = -INFINITY;
    float lsum = 0.f;

    // prologue: stage K(0) -> buf0, load V(0) frags
    bf16x8 vcur[4], vnxt[4];
#pragma unroll
    for (int j = 0; j < 4; ++j)
        gload16(Kp + (long)(j*8 + srow) * DIM + ssw, kbase + j*1024 + lane*16);
#pragma unroll
    for (int f = 0; f < 4; ++f)
        vcur[f] = *reinterpret_cast<const bf16x8*>(Vfp + f*512 + lane*8);

#pragma unroll 2
    for (int n = 0; n < 32; ++n) {
        // ---- issue next-iter loads (stay in flight across this iter) ----
        if (n < 31) {
            const __bf16* kp = Kp + (long)((n + 1) * 32) * DIM;
            char* kdst = kbase + ((n & 1) ^ 1) * 4096;
#pragma unroll
            for (int j = 0; j < 4; ++j)
                gload16(kp + (long)(j*8 + srow) * DIM + ssw, kdst + j*1024 + lane*16);
            const __bf16* vp = Vfp + (long)(n + 1) * 2048;
#pragma unroll
            for (int f = 0; f < 4; ++f)
                vnxt[f] = *reinterpret_cast<const bf16x8*>(vp + f*512 + lane*8);
            asm volatile("s_waitcnt vmcnt(8)" ::: "memory");
        } else {
            asm volatile("s_waitcnt vmcnt(0)" ::: "memory");
        }
        __builtin_amdgcn_sched_barrier(0);

        // ---- QK^T: one 32x32 tile, contraction d=64 = 4 MFMA ----
        const char* kb = kbase + (n & 1) * 4096;
        bf16x8 kf0 = *reinterpret_cast<const bf16x8*>(kb + rdo[0]);
        bf16x8 kf1 = *reinterpret_cast<const bf16x8*>(kb + rdo[1]);
        bf16x8 kf2 = *reinterpret_cast<const bf16x8*>(kb + rdo[2]);
        bf16x8 kf3 = *reinterpret_cast<const bf16x8*>(kb + rdo[3]);
        f32x16 s;
#pragma unroll
        for (int r = 0; r < 16; ++r) s[r] = 0.f;
        __builtin_amdgcn_s_setprio(1);
        s = __builtin_amdgcn_mfma_f32_32x32x16_bf16(kf0, qf[0], s, 0, 0, 0);
        s = __builtin_amdgcn_mfma_f32_32x32x16_bf16(kf1, qf[1], s, 0, 0, 0);
        s = __builtin_amdgcn_mfma_f32_32x32x16_bf16(kf2, qf[2], s, 0, 0, 0);
        s = __builtin_amdgcn_mfma_f32_32x32x16_bf16(kf3, qf[3], s, 0, 0, 0);
        __builtin_amdgcn_s_setprio(0);
        // s[r] = score_log2(q = l31, k = n*32 + (r&3)+8*(r>>2)+4*hi)

        // ---- online softmax (log2 domain), all in-lane for q = l31 ----
        float tmax = s[0];
#pragma unroll
        for (int r = 1; r < 16; ++r) tmax = fmaxf(tmax, s[r]);
        tmax = fmaxf(tmax, __shfl_xor(tmax, 32));

        if (!__all(tmax <= mrun)) {
            const float mnew = fmaxf(mrun, tmax);
            const float corr = fast_exp2(mrun - mnew);   // first iter: 0
            lsum *= corr;
#pragma unroll
            for (int r = 0; r < 16; ++r) {
                const float cr = __shfl(corr, (r&3) + 8*(r>>2) + 4*hi);
                acc[0][r] *= cr;
                acc[1][r] *= cr;
            }
            mrun = mnew;
        }

#pragma unroll
        for (int r = 0; r < 16; ++r) {
            const float p = fast_exp2(s[r] - mrun);
            s[r] = p;
            lsum += p;
        }

        // ---- P pack: A-frag k-pattern == C-layout pattern -> in-lane ----
        bf16x8 pa0, pa1;
#pragma unroll
        for (int e = 0; e < 8; ++e) { pa0[e] = (__bf16)s[e]; pa1[e] = (__bf16)s[8 + e]; }

        // ---- PV: 2 d-tiles x 2 k-slices ----
        __builtin_amdgcn_s_setprio(1);
        acc[0] = __builtin_amdgcn_mfma_f32_32x32x16_bf16(pa0, vcur[0], acc[0], 0, 0, 0);
        acc[1] = __builtin_amdgcn_mfma_f32_32x32x16_bf16(pa0, vcur[1], acc[1], 0, 0, 0);
        acc[0] = __builtin_amdgcn_mfma_f32_32x32x16_bf16(pa1, vcur[2], acc[0], 0, 0, 0);
        acc[1] = __builtin_amdgcn_mfma_f32_32x32x16_bf16(pa1, vcur[3], acc[1], 0, 0, 0);
        __builtin_amdgcn_s_setprio(0);

#pragma unroll
        for (int f = 0; f < 4; ++f) vcur[f] = vnxt[f];
    }

    // full row-sum per lane
    lsum += __shfl_xor(lsum, 32);

    // ---- 4-way k-merge through LDS (only sync points in the kernel) ----
    __syncthreads();   // all waves done reading their K bufs
    float* lacc = (float*)smem;                 // [3][32][64] f32 = 24KB
    float* lm   = (float*)(smem + 24576);       // [3][32]
    float* ll   = (float*)(smem + 24960);       // [3][32]

    if (w > 0) {
        const int wp = w - 1;
        if (lane < 32) { lm[wp*32 + lane] = mrun; ll[wp*32 + lane] = lsum; }
#pragma unroll
        for (int n0 = 0; n0 < 2; ++n0)
#pragma unroll
            for (int r = 0; r < 16; ++r) {
                const int q = (r&3) + 8*(r>>2) + 4*hi;
                lacc[(wp*32 + q)*64 + n0*32 + l31] = acc[n0][r];
            }
    }
    __syncthreads();

    if (w == 0) {
#pragma unroll
        for (int r = 0; r < 16; ++r) {
            const int q = (r&3) + 8*(r>>2) + 4*hi;
            const float mo = __shfl(mrun, q);
            const float lo = __shfl(lsum, q);
            const float m1 = lm[q],      l1 = ll[q];
            const float m2 = lm[32 + q], l2 = ll[32 + q];
            const float m3 = lm[64 + q], l3 = ll[64 + q];
            const float M  = fmaxf(fmaxf(mo, m1), fmaxf(m2, m3));
            const float f0 = fast_exp2(mo - M);
            const float f1 = fast_exp2(m1 - M);
            const float f2 = fast_exp2(m2 - M);
            const float f3 = fast_exp2(m3 - M);
            const float inv = 1.f / (lo*f0 + l1*f1 + l2*f2 + l3*f3);
            const long rowg = (long)b * SEQ + qbase + q;
#pragma unroll
            for (int n0 = 0; n0 < 2; ++n0) {
                const int d = n0*32 + l31;
                const float val = acc[n0][r]*f0
                    + lacc[(q)*64 + d]*f1
                    + lacc[(32 + q)*64 + d]*f2
                    + lacc[(64 + q)*64 + d]*f3;
                out[rowg * DIM + d] = val * inv;
            }
        }
    }
}

// ---------------------------------------------------------------------------
extern "C" void kernel_launch(void* const* d_in, const int* in_sizes, int n_in,
                              void* d_out, int out_size, void* d_ws, size_t ws_size,
                              hipStream_t stream)
{
    const float* x = (const float*)d_in[0];
    const float* w = (const float*)d_in[1];
    float* out = (float*)d_out;

    char* ws = (char*)d_ws;
    const size_t sz = (size_t)NB * SEQ * DIM * sizeof(__bf16);  // 2 MiB each
    __bf16* Qb  = (__bf16*)(ws);
    __bf16* Kb  = (__bf16*)(ws + sz);
    __bf16* Vf  = (__bf16*)(ws + 2 * sz);               // frag-major V, 2 MiB
    __bf16* WT  = (__bf16*)(ws + 3 * sz);               // 24 KiB
    float*  peb = (float*)(ws + 3 * sz + 32 * 1024);    // 1 MiB

    wprep_kernel<<<3 * DIM * DIM / 256, 256, 0, stream>>>(w, WT);
    pe_prep_kernel<<<SEQ * DIM / 256, 256, 0, stream>>>(peb);

    qkv_prep_kernel<<<NB * SEQ / 64, 256, 0, stream>>>(x, WT, peb, Qb, Kb, Vf);

    attn_kernel<<<NB * SEQ / 32, 256, 0, stream>>>(Qb, Kb, Vf, out);
}